// Round 6
// baseline (325.455 us; speedup 1.0000x reference)
//
#include <hip/hip_runtime.h>
#include <hip/hip_bf16.h>

// SynthesisBlock: modulated 3x3 conv (StyleGAN2-style) on MI355X.
// R6 = R5 + explicitly software-pipelined inner loop:
//   prefetch bq(dx,ir+1) before MFMA(dx,ir); prefetch a(dx+1) under the
//   dx tail; all register indices static. setprio(1) around MFMA clusters.
//   Goal: overlap LDS-read pipe (4032 cyc/CU/step) with MFMA (4651).

typedef float f32x4 __attribute__((ext_vector_type(4)));
typedef float f32x16 __attribute__((ext_vector_type(16)));
typedef short bf16x8 __attribute__((ext_vector_type(8)));
typedef int i32x4 __attribute__((ext_vector_type(4)));

#define BB 16
#define CIN 512
#define COUT 512
#define HH 64
#define WW 64
#define LL 512

// xs3: [b 16][c16 32][rowidx 66 (= y+1)][h 2][px' 68][ci8 8] bf16
#define X3ROWB 2176
#define X3C16B (66 * X3ROWB)            // 143616
#define X3BB (32 * X3C16B)              // 4595712
#define XS3_SZ (16 * X3BB)              // 73531392

// wt3: [cib 32][tap 9][h 2][co 512][ci8 8] bf16
#define WT3_STEPB 147456
#define WT3_SZ (32 * WT3_STEPB)

#define XS3_OFF 0
#define WT3_OFF XS3_SZ
#define STYLE_OFF (WT3_OFF + WT3_SZ)
#define STYLE_SZ (BB * CIN * 4)
#define WSQ_OFF (STYLE_OFF + STYLE_SZ)
#define WSQ_SZ (COUT * CIN * 4)
#define DEM_OFF (WSQ_OFF + WSQ_SZ)
#define DEM_SZ (BB * COUT * 4)
#define WS_NEEDED (DEM_OFF + DEM_SZ)

#define XSTEPB 22528
#define WSTEPB 18432

__device__ __forceinline__ void gld_lds16(const void* g, void* l) {
  __builtin_amdgcn_global_load_lds(
      (const __attribute__((address_space(1))) unsigned int*)g,
      (__attribute__((address_space(3))) unsigned int*)l, 16, 0, 0);
}

// ---------------- K1: style ----------------
__global__ void style_kernel(const float* __restrict__ latent,
                             const float* __restrict__ affine_w,
                             const float* __restrict__ affine_b,
                             float* __restrict__ style) {
  const int idx = blockIdx.x * 256 + threadIdx.x;   // 8192
  const int b = idx >> 9, ci = idx & 511;
  const float* lp = latent + b * LL;
  const float* wp = affine_w + ci * LL;
  float acc = 0.f;
  for (int l = 0; l < LL; ++l) acc += lp[l] * wp[l];
  style[idx] = acc * 0.044194173824159216f + affine_b[ci];  // sqrt(1/512)
}

// ---------------- K2: weight sumsq + wt3 layout ----------------
__global__ void wprep_kernel(const float* __restrict__ conv_w,
                             float* __restrict__ wsq,
                             __hip_bfloat16* __restrict__ wt3) {
  const int idx = blockIdx.x * 256 + threadIdx.x;   // 262144 = co*512+ci
  const int co = idx >> 9, ci = idx & 511;
  const float* wp = conv_w + idx * 9;
  const int cib = ci >> 4, h = (ci >> 3) & 1, ci8 = ci & 7;
  __hip_bfloat16* base = wt3 + (size_t)cib * 73728 + h * 4096 + co * 8 + ci8;
  float ss = 0.f;
#pragma unroll
  for (int t = 0; t < 9; ++t) {
    float v = wp[t];
    ss += v * v;
    base[t * 8192] = __float2bfloat16(v);
  }
  wsq[idx] = ss;
}

// ---------------- K3: demodulation scale ----------------
__global__ void dem_kernel(const float* __restrict__ wsq,
                           const float* __restrict__ style,
                           float* __restrict__ dem) {
  const int idx = blockIdx.x * 256 + threadIdx.x;   // 8192 = b*512+co
  const int b = idx >> 9, co = idx & 511;
  const float* sp = style + b * CIN;
  const float* wp = wsq + co * CIN;
  float acc = 0.f;
  for (int ci = 0; ci < CIN; ++ci) {
    float s = sp[ci];
    acc += wp[ci] * s * s;
  }
  dem[idx] = 1.0f / sqrtf(acc + 1e-8f);
}

// ---------------- K4: modulate + transpose to xs3 ----------------
__global__ void xsprep_kernel(const float* __restrict__ content,
                              const float* __restrict__ style,
                              char* __restrict__ xs3) {
  __shared__ float tile[64][65];
  const int b = blockIdx.x >> 6;
  const int y = blockIdx.x & 63;
  const int tid = threadIdx.x;
  char* bbase = xs3 + (size_t)b * X3BB;

  {
    const int c16 = tid >> 3, rest = tid & 7;
    const int h = rest >> 2, pp = rest & 3;
    const int px = (pp == 0) ? 0 : 64 + pp;
    *(i32x4*)(bbase + (size_t)c16 * X3C16B + (y + 1) * X3ROWB + h * 1088 +
              px * 16) = (i32x4){0, 0, 0, 0};
  }
  if (y == 0 || y == 63) {
    const int rowidx = (y == 0) ? 0 : 65;
#pragma unroll
    for (int k = 0; k < 17; ++k) {
      const int u = tid + k * 256;
      if (u < 4352) {
        const int c16 = u / 136, w = u - c16 * 136;
        *(i32x4*)(bbase + (size_t)c16 * X3C16B + rowidx * X3ROWB + w * 16) =
            (i32x4){0, 0, 0, 0};
      }
    }
  }

  for (int cb = 0; cb < 8; ++cb) {
    const int ci0 = cb * 64;
    __syncthreads();
    {
      const int x = tid & 63;
      const int c0 = tid >> 6;
#pragma unroll
      for (int p = 0; p < 16; ++p) {
        const int ci = p * 4 + c0;
        tile[ci][x] = content[((b * CIN + ci0 + ci) * HH + y) * WW + x];
      }
    }
    __syncthreads();
    {
      const int x = tid & 63;
      const int o4 = tid >> 6;
#pragma unroll
      for (int oo = 0; oo < 2; ++oo) {
        const int oct = o4 * 2 + oo;
        const int c16 = cb * 4 + (oct >> 1);
        const int h = oct & 1;
        bf16x8 v;
#pragma unroll
        for (int j = 0; j < 8; ++j) {
          const float st = style[b * CIN + ci0 + oct * 8 + j];
          v[j] = __bfloat16_as_short(
              __float2bfloat16(tile[oct * 8 + j][x] * st));
        }
        *(bf16x8*)(bbase + (size_t)c16 * X3C16B + (y + 1) * X3ROWB + h * 1088 +
                   (x + 1) * 16) = v;
      }
    }
  }
}

// ---------------- K5: main MFMA conv ----------------
__global__ __launch_bounds__(256, 2) void conv_kernel(
    const char* __restrict__ xs3,
    const char* __restrict__ wt3,
    const float* __restrict__ dem,
    const float* __restrict__ noise,
    const float* __restrict__ biasp,
    const float* __restrict__ nwp,
    float* __restrict__ out) {
  __shared__ __attribute__((aligned(16))) char xlds[2][XSTEPB];
  __shared__ __attribute__((aligned(16))) char wlds[2][WSTEPB];

  const int tid = threadIdx.x;
  const int lane = tid & 63;
  const int wv = tid >> 6;
  const int l31 = lane & 31;
  const int hsel = lane >> 5;

  const int d = blockIdx.x;                 // 0..1023
  const int L = (d & 7) * 128 + (d >> 3);   // bijective XCD swizzle
  const int cot = L & 7;
  const int yo = (L >> 3) & 7;
  const int b = L >> 6;
  const int co0 = cot << 6;
  const int y0 = yo << 3;

  const char* xsrc[6];
#pragma unroll
  for (int k = 0; k < 6; ++k) {
    const int c = wv + 4 * k;
    if (c < 22) {
      const int beta = c * 1024 + lane * 16;
      const int row = beta / X3ROWB;
      const int within = beta - row * X3ROWB;
      xsrc[k] = xs3 + (size_t)(b * 32) * X3C16B +
                (size_t)(y0 + row) * X3ROWB + within;
    } else {
      xsrc[k] = xs3;
    }
  }
  const char* wsrc[5];
#pragma unroll
  for (int k = 0; k < 5; ++k) {
    const int c = wv + 4 * k;
    if (c < 18) {
      const int tap = c >> 1, h = c & 1;
      wsrc[k] = wt3 + tap * 16384 + h * 8192 + (co0 + lane) * 16;
    } else {
      wsrc[k] = wt3;
    }
  }

  const int abase0 = hsel * 1024 + l31 * 16;  // + tap*2048 + mf*512
  const int bbase0 = hsel * 1088 + l31 * 16;  // + ir*2176 + (q*32+dx)*16
  const int xwrow = 2 * wv * X3ROWB;

  f32x16 acc[2][2][2];
#pragma unroll
  for (int mf = 0; mf < 2; ++mf)
#pragma unroll
    for (int r = 0; r < 2; ++r)
#pragma unroll
      for (int q = 0; q < 2; ++q)
#pragma unroll
        for (int e = 0; e < 16; ++e) acc[mf][r][q][e] = 0.f;

  auto stage = [&](int t, int bi) {
    char* xd = xlds[bi];
    char* wd = wlds[bi];
    const size_t xadv = (size_t)t * X3C16B;
    const size_t wadv = (size_t)t * WT3_STEPB;
#pragma unroll
    for (int k = 0; k < 6; ++k) {
      const int c = wv + 4 * k;
      if (c < 22) gld_lds16(xsrc[k] + xadv, xd + c * 1024);
    }
#pragma unroll
    for (int k = 0; k < 5; ++k) {
      const int c = wv + 4 * k;
      if (c < 18) gld_lds16(wsrc[k] + wadv, wd + c * 1024);
    }
  };

  stage(0, 0);
  __syncthreads();

  // ---- software-pipelined K-loop ----
  // RDA: 6 A-frag reads (dx fixed); RDB: 2 B-frag reads (dx, ir fixed);
  // MM: MFMA cluster for (dx, ir) using aC/bC. All indices compile-time.
#define RDA(dst, DX)                                                     \
  {                                                                      \
    _Pragma("unroll") for (int dy = 0; dy < 3; ++dy)                     \
        _Pragma("unroll") for (int mf = 0; mf < 2; ++mf)                 \
            dst[dy][mf] = *(const bf16x8*)(wb + (dy * 3 + (DX)) * 2048 + \
                                           abase0 + mf * 512);           \
  }
#define RDB(dst, DX, IR)                                                  \
  {                                                                       \
    _Pragma("unroll") for (int q = 0; q < 2; ++q)                         \
        dst[q] = *(const bf16x8*)(xb + xwrow + (IR) * X3ROWB + bbase0 +   \
                                  (q * 32 + (DX)) * 16);                  \
  }
#define MM(DX, IR)                                                        \
  {                                                                       \
    __builtin_amdgcn_s_setprio(1);                                        \
    _Pragma("unroll") for (int dy = 0; dy < 3; ++dy) {                    \
      const int rr = (IR)-dy;                                             \
      if (rr == 0 || rr == 1) {                                           \
        _Pragma("unroll") for (int q = 0; q < 2; ++q)                     \
            _Pragma("unroll") for (int mf = 0; mf < 2; ++mf)              \
                acc[mf][rr][q] = __builtin_amdgcn_mfma_f32_32x32x16_bf16( \
                    aC[dy][mf], bC[q], acc[mf][rr][q], 0, 0, 0);          \
      }                                                                   \
    }                                                                     \
    __builtin_amdgcn_s_setprio(0);                                        \
  }
#define CPB { bC[0] = bN[0]; bC[1] = bN[1]; }
#define CPA                                                  \
  {                                                          \
    _Pragma("unroll") for (int dy = 0; dy < 3; ++dy)         \
        _Pragma("unroll") for (int mf = 0; mf < 2; ++mf)     \
            aC[dy][mf] = aN[dy][mf];                         \
  }

  for (int t = 0; t < 32; ++t) {
    const int bi = t & 1;
    if (t < 31) stage(t + 1, bi ^ 1);   // loads in flight during compute
    const char* xb = xlds[bi];
    const char* wb = wlds[bi];

    bf16x8 aC[3][2], aN[3][2], bC[2], bN[2];
    RDA(aC, 0);
    RDB(bC, 0, 0);
    // dx = 0
    RDB(bN, 0, 1); MM(0, 0); CPB;
    RDB(bN, 0, 2); MM(0, 1); CPB;
    RDB(bN, 0, 3); MM(0, 2); CPB;
    RDA(aN, 1); RDB(bN, 1, 0); MM(0, 3); CPA; CPB;
    // dx = 1
    RDB(bN, 1, 1); MM(1, 0); CPB;
    RDB(bN, 1, 2); MM(1, 1); CPB;
    RDB(bN, 1, 3); MM(1, 2); CPB;
    RDA(aN, 2); RDB(bN, 2, 0); MM(1, 3); CPA; CPB;
    // dx = 2
    RDB(bN, 2, 1); MM(2, 0); CPB;
    RDB(bN, 2, 2); MM(2, 1); CPB;
    RDB(bN, 2, 3); MM(2, 2); CPB;
    MM(2, 3);

    __syncthreads();   // staged(t+1) landed + all reads of buf bi done
  }
#undef RDA
#undef RDB
#undef MM
#undef CPB
#undef CPA

  // ---- epilogue: demod scale, noise, bias, lrelu*sqrt(2) ----
  const float nwv = nwp[0];
  float nz[2][2];
#pragma unroll
  for (int r = 0; r < 2; ++r) {
    const int y = y0 + 2 * wv + r;
#pragma unroll
    for (int q = 0; q < 2; ++q)
      nz[r][q] = nwv * noise[(b << 12) + (y << 6) + q * 32 + l31];
  }
#pragma unroll
  for (int mf = 0; mf < 2; ++mf)
#pragma unroll
    for (int reg = 0; reg < 16; ++reg) {
      const int coo = (reg & 3) + 8 * (reg >> 2) + 4 * hsel;
      const int co = co0 + mf * 32 + coo;
      const float dv = dem[(b << 9) + co];
      const float bv = biasp[co];
#pragma unroll
      for (int r = 0; r < 2; ++r) {
        const int y = y0 + 2 * wv + r;
#pragma unroll
        for (int q = 0; q < 2; ++q) {
          float v = acc[mf][r][q][reg] * dv + nz[r][q] + bv;
          v = (v > 0.f ? v : 0.2f * v) * 1.41421356237309515f;
          out[(((size_t)(b << 9) + co) << 12) + (y << 6) + q * 32 + l31] = v;
        }
      }
    }
}

extern "C" void kernel_launch(void* const* d_in, const int* in_sizes, int n_in,
                              void* d_out, int out_size, void* d_ws, size_t ws_size,
                              hipStream_t stream) {
  const float* content  = (const float*)d_in[0];
  const float* latent   = (const float*)d_in[1];
  const float* noise    = (const float*)d_in[2];
  const float* affine_w = (const float*)d_in[3];
  const float* affine_b = (const float*)d_in[4];
  const float* conv_w   = (const float*)d_in[5];
  const float* bias     = (const float*)d_in[6];
  const float* nw       = (const float*)d_in[7];
  float* out = (float*)d_out;
  char* ws = (char*)d_ws;

  if (ws_size < (size_t)WS_NEEDED) return;

  char* xs3 = ws + XS3_OFF;
  __hip_bfloat16* wt3 = (__hip_bfloat16*)(ws + WT3_OFF);
  float* style = (float*)(ws + STYLE_OFF);
  float* wsq   = (float*)(ws + WSQ_OFF);
  float* dem   = (float*)(ws + DEM_OFF);

  style_kernel<<<dim3(32), dim3(256), 0, stream>>>(latent, affine_w, affine_b, style);
  wprep_kernel<<<dim3(1024), dim3(256), 0, stream>>>(conv_w, wsq, wt3);
  dem_kernel<<<dim3(32), dim3(256), 0, stream>>>(wsq, style, dem);
  xsprep_kernel<<<dim3(1024), dim3(256), 0, stream>>>(content, style, xs3);
  conv_kernel<<<dim3(1024), dim3(256), 0, stream>>>(
      xs3, (const char*)(ws + WT3_OFF), dem, noise, bias, nw, out);
}

// Round 7
// 316.607 us; speedup vs baseline: 1.0279x; 1.0279x over previous
//
#include <hip/hip_runtime.h>
#include <hip/hip_bf16.h>

// SynthesisBlock: modulated 3x3 conv (StyleGAN2-style) on MI355X.
// R7 = R5 data plan + 8-phase-style schedule (T3+T4+T5):
//   per 16-ci step: 3 phases (dx=0,1,2), each
//     {ds_read 14 frags; issue 1/3 of stage(t+1); s_barrier;
//      lgkmcnt(0)+sched_barrier; setprio(1); 24 MFMA; setprio(0); s_barrier}
//   vmcnt(0) once per step end (stage loads in flight across phases).

typedef float f32x4 __attribute__((ext_vector_type(4)));
typedef float f32x16 __attribute__((ext_vector_type(16)));
typedef short bf16x8 __attribute__((ext_vector_type(8)));
typedef int i32x4 __attribute__((ext_vector_type(4)));

#define BB 16
#define CIN 512
#define COUT 512
#define HH 64
#define WW 64
#define LL 512

// xs3: [b 16][c16 32][rowidx 66 (= y+1)][h 2][px' 68][ci8 8] bf16
#define X3ROWB 2176
#define X3C16B (66 * X3ROWB)            // 143616
#define X3BB (32 * X3C16B)              // 4595712
#define XS3_SZ (16 * X3BB)              // 73531392

// wt3: [cib 32][tap 9][h 2][co 512][ci8 8] bf16
#define WT3_STEPB 147456
#define WT3_SZ (32 * WT3_STEPB)

#define XS3_OFF 0
#define WT3_OFF XS3_SZ
#define STYLE_OFF (WT3_OFF + WT3_SZ)
#define STYLE_SZ (BB * CIN * 4)
#define WSQ_OFF (STYLE_OFF + STYLE_SZ)
#define WSQ_SZ (COUT * CIN * 4)
#define DEM_OFF (WSQ_OFF + WSQ_SZ)
#define DEM_SZ (BB * COUT * 4)
#define WS_NEEDED (DEM_OFF + DEM_SZ)

#define XSTEPB 22528
#define WSTEPB 18432

__device__ __forceinline__ void gld_lds16(const void* g, void* l) {
  __builtin_amdgcn_global_load_lds(
      (const __attribute__((address_space(1))) unsigned int*)g,
      (__attribute__((address_space(3))) unsigned int*)l, 16, 0, 0);
}

// ---------------- K1: style ----------------
__global__ void style_kernel(const float* __restrict__ latent,
                             const float* __restrict__ affine_w,
                             const float* __restrict__ affine_b,
                             float* __restrict__ style) {
  const int idx = blockIdx.x * 256 + threadIdx.x;   // 8192
  const int b = idx >> 9, ci = idx & 511;
  const float* lp = latent + b * LL;
  const float* wp = affine_w + ci * LL;
  float acc = 0.f;
  for (int l = 0; l < LL; ++l) acc += lp[l] * wp[l];
  style[idx] = acc * 0.044194173824159216f + affine_b[ci];  // sqrt(1/512)
}

// ---------------- K2: weight sumsq + wt3 layout ----------------
__global__ void wprep_kernel(const float* __restrict__ conv_w,
                             float* __restrict__ wsq,
                             __hip_bfloat16* __restrict__ wt3) {
  const int idx = blockIdx.x * 256 + threadIdx.x;   // 262144 = co*512+ci
  const int co = idx >> 9, ci = idx & 511;
  const float* wp = conv_w + idx * 9;
  const int cib = ci >> 4, h = (ci >> 3) & 1, ci8 = ci & 7;
  __hip_bfloat16* base = wt3 + (size_t)cib * 73728 + h * 4096 + co * 8 + ci8;
  float ss = 0.f;
#pragma unroll
  for (int t = 0; t < 9; ++t) {
    float v = wp[t];
    ss += v * v;
    base[t * 8192] = __float2bfloat16(v);
  }
  wsq[idx] = ss;
}

// ---------------- K3: demodulation scale ----------------
__global__ void dem_kernel(const float* __restrict__ wsq,
                           const float* __restrict__ style,
                           float* __restrict__ dem) {
  const int idx = blockIdx.x * 256 + threadIdx.x;   // 8192 = b*512+co
  const int b = idx >> 9, co = idx & 511;
  const float* sp = style + b * CIN;
  const float* wp = wsq + co * CIN;
  float acc = 0.f;
  for (int ci = 0; ci < CIN; ++ci) {
    float s = sp[ci];
    acc += wp[ci] * s * s;
  }
  dem[idx] = 1.0f / sqrtf(acc + 1e-8f);
}

// ---------------- K4: modulate + transpose to xs3 ----------------
__global__ void xsprep_kernel(const float* __restrict__ content,
                              const float* __restrict__ style,
                              char* __restrict__ xs3) {
  __shared__ float tile[64][65];
  const int b = blockIdx.x >> 6;
  const int y = blockIdx.x & 63;
  const int tid = threadIdx.x;
  char* bbase = xs3 + (size_t)b * X3BB;

  {
    const int c16 = tid >> 3, rest = tid & 7;
    const int h = rest >> 2, pp = rest & 3;
    const int px = (pp == 0) ? 0 : 64 + pp;
    *(i32x4*)(bbase + (size_t)c16 * X3C16B + (y + 1) * X3ROWB + h * 1088 +
              px * 16) = (i32x4){0, 0, 0, 0};
  }
  if (y == 0 || y == 63) {
    const int rowidx = (y == 0) ? 0 : 65;
#pragma unroll
    for (int k = 0; k < 17; ++k) {
      const int u = tid + k * 256;
      if (u < 4352) {
        const int c16 = u / 136, w = u - c16 * 136;
        *(i32x4*)(bbase + (size_t)c16 * X3C16B + rowidx * X3ROWB + w * 16) =
            (i32x4){0, 0, 0, 0};
      }
    }
  }

  for (int cb = 0; cb < 8; ++cb) {
    const int ci0 = cb * 64;
    __syncthreads();
    {
      const int x = tid & 63;
      const int c0 = tid >> 6;
#pragma unroll
      for (int p = 0; p < 16; ++p) {
        const int ci = p * 4 + c0;
        tile[ci][x] = content[((b * CIN + ci0 + ci) * HH + y) * WW + x];
      }
    }
    __syncthreads();
    {
      const int x = tid & 63;
      const int o4 = tid >> 6;
#pragma unroll
      for (int oo = 0; oo < 2; ++oo) {
        const int oct = o4 * 2 + oo;
        const int c16 = cb * 4 + (oct >> 1);
        const int h = oct & 1;
        bf16x8 v;
#pragma unroll
        for (int j = 0; j < 8; ++j) {
          const float st = style[b * CIN + ci0 + oct * 8 + j];
          v[j] = __bfloat16_as_short(
              __float2bfloat16(tile[oct * 8 + j][x] * st));
        }
        *(bf16x8*)(bbase + (size_t)c16 * X3C16B + (y + 1) * X3ROWB + h * 1088 +
                   (x + 1) * 16) = v;
      }
    }
  }
}

// ---------------- K5: main MFMA conv ----------------
__global__ __launch_bounds__(256, 2) void conv_kernel(
    const char* __restrict__ xs3,
    const char* __restrict__ wt3,
    const float* __restrict__ dem,
    const float* __restrict__ noise,
    const float* __restrict__ biasp,
    const float* __restrict__ nwp,
    float* __restrict__ out) {
  __shared__ __attribute__((aligned(16))) char xlds[2][XSTEPB];
  __shared__ __attribute__((aligned(16))) char wlds[2][WSTEPB];

  const int tid = threadIdx.x;
  const int lane = tid & 63;
  const int wv = tid >> 6;
  const int l31 = lane & 31;
  const int hsel = lane >> 5;

  const int d = blockIdx.x;                 // 0..1023
  const int L = (d & 7) * 128 + (d >> 3);   // bijective XCD swizzle
  const int cot = L & 7;
  const int yo = (L >> 3) & 7;
  const int b = L >> 6;
  const int co0 = cot << 6;
  const int y0 = yo << 3;

  // X chunk sources (step 0); chunk index c = wv + 4k, dest off c*1024
  const char* xsrc[6];
#pragma unroll
  for (int k = 0; k < 6; ++k) {
    const int c = wv + 4 * k;
    if (c < 22) {
      const int beta = c * 1024 + lane * 16;
      const int row = beta / X3ROWB;
      const int within = beta - row * X3ROWB;
      xsrc[k] = xs3 + (size_t)(b * 32) * X3C16B +
                (size_t)(y0 + row) * X3ROWB + within;
    } else {
      xsrc[k] = xs3;
    }
  }
  const char* wsrc[5];
#pragma unroll
  for (int k = 0; k < 5; ++k) {
    const int c = wv + 4 * k;
    if (c < 18) {
      const int tap = c >> 1, h = c & 1;
      wsrc[k] = wt3 + tap * 16384 + h * 8192 + (co0 + lane) * 16;
    } else {
      wsrc[k] = wt3;
    }
  }

  const int abase0 = hsel * 1024 + l31 * 16;  // + tap*2048 + mf*512
  const int bbase0 = hsel * 1088 + l31 * 16;  // + ir*2176 + (q*32+dx)*16
  const int xwrow = 2 * wv * X3ROWB;

  f32x16 acc[2][2][2];
#pragma unroll
  for (int mf = 0; mf < 2; ++mf)
#pragma unroll
    for (int r = 0; r < 2; ++r)
#pragma unroll
      for (int q = 0; q < 2; ++q)
#pragma unroll
        for (int e = 0; e < 16; ++e) acc[mf][r][q][e] = 0.f;

  // stage sub-parts: X chunks k / W chunks k for ci-step ts into buffer ptrs
#define STG_X(K)                                                        \
  if ((K) < 5 || wv < 2)                                                \
    gld_lds16(xsrc[K] + xadv, xd + (wv + 4 * (K)) * 1024);
#define STG_W(K)                                                        \
  if ((K) < 4 || wv < 2)                                                \
    gld_lds16(wsrc[K] + wadv, wd + (wv + 4 * (K)) * 1024);

  // full stage (prologue)
  {
    char* xd = xlds[0];
    char* wd = wlds[0];
    const size_t xadv = 0, wadv = 0;
    STG_X(0) STG_X(1) STG_X(2) STG_X(3) STG_X(4) STG_X(5)
    STG_W(0) STG_W(1) STG_W(2) STG_W(3) STG_W(4)
  }
  asm volatile("s_waitcnt vmcnt(0)" ::: "memory");
  __builtin_amdgcn_s_barrier();

  // phase: read 6 A + 8 B frags, issue stage part, barrier, drain-lgkm,
  // 24 MFMA under setprio(1), barrier.
#define PHASE(DX, STGPART, TAIL)                                          \
  {                                                                       \
    bf16x8 aP[3][2], bP[4][2];                                            \
    _Pragma("unroll") for (int dy = 0; dy < 3; ++dy)                      \
        _Pragma("unroll") for (int mf = 0; mf < 2; ++mf)                  \
            aP[dy][mf] = *(const bf16x8*)(wb + (dy * 3 + (DX)) * 2048 +   \
                                          abase0 + mf * 512);             \
    _Pragma("unroll") for (int ir = 0; ir < 4; ++ir)                      \
        _Pragma("unroll") for (int q = 0; q < 2; ++q)                     \
            bP[ir][q] = *(const bf16x8*)(xb + xwrow + ir * X3ROWB +       \
                                         bbase0 + (q * 32 + (DX)) * 16);  \
    if (t < 31) { STGPART }                                               \
    __builtin_amdgcn_s_barrier();                                         \
    asm volatile("s_waitcnt lgkmcnt(0)" ::: "memory");                    \
    __builtin_amdgcn_sched_barrier(0);                                    \
    __builtin_amdgcn_s_setprio(1);                                        \
    _Pragma("unroll") for (int ir = 0; ir < 4; ++ir)                      \
        _Pragma("unroll") for (int dy = 0; dy < 3; ++dy) {                \
      const int rr = ir - dy;                                             \
      if (rr == 0 || rr == 1) {                                           \
        _Pragma("unroll") for (int q = 0; q < 2; ++q)                     \
            _Pragma("unroll") for (int mf = 0; mf < 2; ++mf)              \
                acc[mf][rr][q] = __builtin_amdgcn_mfma_f32_32x32x16_bf16( \
                    aP[dy][mf], bP[ir][q], acc[mf][rr][q], 0, 0, 0);      \
      }                                                                   \
    }                                                                     \
    __builtin_amdgcn_s_setprio(0);                                        \
    TAIL;                                                                 \
    __builtin_amdgcn_s_barrier();                                         \
  }

  for (int t = 0; t < 32; ++t) {
    const int bi = t & 1;
    const char* xb = xlds[bi];
    const char* wb = wlds[bi];
    char* xd = xlds[bi ^ 1];
    char* wd = wlds[bi ^ 1];
    const size_t xadv = (size_t)(t + 1) * X3C16B;
    const size_t wadv = (size_t)(t + 1) * WT3_STEPB;

    PHASE(0, STG_X(0) STG_X(1) STG_W(0) STG_W(1), )
    PHASE(1, STG_X(2) STG_X(3) STG_W(2) STG_W(3), )
    PHASE(2, STG_X(4) STG_X(5) STG_W(4),
          asm volatile("s_waitcnt vmcnt(0)" ::: "memory"))
  }
#undef PHASE
#undef STG_X
#undef STG_W

  // ---- epilogue: demod scale, noise, bias, lrelu*sqrt(2) ----
  const float nwv = nwp[0];
  float nz[2][2];
#pragma unroll
  for (int r = 0; r < 2; ++r) {
    const int y = y0 + 2 * wv + r;
#pragma unroll
    for (int q = 0; q < 2; ++q)
      nz[r][q] = nwv * noise[(b << 12) + (y << 6) + q * 32 + l31];
  }
#pragma unroll
  for (int mf = 0; mf < 2; ++mf)
#pragma unroll
    for (int reg = 0; reg < 16; ++reg) {
      const int coo = (reg & 3) + 8 * (reg >> 2) + 4 * hsel;
      const int co = co0 + mf * 32 + coo;
      const float dv = dem[(b << 9) + co];
      const float bv = biasp[co];
#pragma unroll
      for (int r = 0; r < 2; ++r) {
        const int y = y0 + 2 * wv + r;
#pragma unroll
        for (int q = 0; q < 2; ++q) {
          float v = acc[mf][r][q][reg] * dv + nz[r][q] + bv;
          v = (v > 0.f ? v : 0.2f * v) * 1.41421356237309515f;
          out[(((size_t)(b << 9) + co) << 12) + (y << 6) + q * 32 + l31] = v;
        }
      }
    }
}

extern "C" void kernel_launch(void* const* d_in, const int* in_sizes, int n_in,
                              void* d_out, int out_size, void* d_ws, size_t ws_size,
                              hipStream_t stream) {
  const float* content  = (const float*)d_in[0];
  const float* latent   = (const float*)d_in[1];
  const float* noise    = (const float*)d_in[2];
  const float* affine_w = (const float*)d_in[3];
  const float* affine_b = (const float*)d_in[4];
  const float* conv_w   = (const float*)d_in[5];
  const float* bias     = (const float*)d_in[6];
  const float* nw       = (const float*)d_in[7];
  float* out = (float*)d_out;
  char* ws = (char*)d_ws;

  if (ws_size < (size_t)WS_NEEDED) return;

  char* xs3 = ws + XS3_OFF;
  __hip_bfloat16* wt3 = (__hip_bfloat16*)(ws + WT3_OFF);
  float* style = (float*)(ws + STYLE_OFF);
  float* wsq   = (float*)(ws + WSQ_OFF);
  float* dem   = (float*)(ws + DEM_OFF);

  style_kernel<<<dim3(32), dim3(256), 0, stream>>>(latent, affine_w, affine_b, style);
  wprep_kernel<<<dim3(1024), dim3(256), 0, stream>>>(conv_w, wsq, wt3);
  dem_kernel<<<dim3(32), dim3(256), 0, stream>>>(wsq, style, dem);
  xsprep_kernel<<<dim3(1024), dim3(256), 0, stream>>>(content, style, xs3);
  conv_kernel<<<dim3(1024), dim3(256), 0, stream>>>(
      xs3, (const char*)(ws + WT3_OFF), dem, noise, bias, nw, out);
}